// Round 11
// baseline (1465.042 us; speedup 1.0000x reference)
//
#include <hip/hip_runtime.h>
#include <hip/hip_bf16.h>

// LSTM classifier: B=64, S=2048, E=H=128, OUT=1.
// Phase A (parallel, MFMA GEMM): pre[t][g][b][j] = bias + emb[x[b,t]].W_g[j][:128]
// Phase B (sequential): round-11 structural change — TWO batches per block
//   (32 blocks x 8 waves). Rationale: step was bound by per-CU matrix
//   serialization (64 M=1-wasted MFMAs = 272 cyc) + serial chain (LDS
//   round-trip ~210 + transcendental tail ~150); r9/r10 proved micro-edits
//   can't touch it. Two independent recurrences per block share the resident
//   weight fragments; batch-1's MFMAs/tail hide batch-0's chain stalls and
//   the barrier amortizes over 2 batches. Expected ~1.4-1.6x on phaseB.

#define LSTM_B 64
#define LSTM_E 128
#define LSTM_H 128
#define ROWW   256           // E+H, weight row width
#define TSTRIDE (2*LSTM_B*LSTM_H)   // floats per timestep in pre buffer

typedef __attribute__((ext_vector_type(8))) short bf16x8;
typedef __attribute__((ext_vector_type(4))) float f32x4;

__device__ __forceinline__ float fast_rcp(float x) {
    return __builtin_amdgcn_rcpf(x);
}
__device__ __forceinline__ float sigmoidf_(float x) {
    return fast_rcp(1.0f + __expf(-x));
}
__device__ __forceinline__ float tanh_fast(float x) {
    float ax = fabsf(x);
    float t = __expf(-2.0f * ax);          // in (0,1], no overflow
    float r = (1.0f - t) * fast_rcp(1.0f + t);
    return copysignf(r, x);
}
__device__ __forceinline__ short f2bf(float f) {   // round-to-nearest-even
    union { float f; unsigned u; } v; v.f = f;
    unsigned r = (v.u + 0x7FFFu + ((v.u >> 16) & 1u)) >> 16;
    return (short)r;
}
__device__ __forceinline__ float bf2f(short s) {
    union { unsigned u; float f; } v; v.u = ((unsigned)(unsigned short)s) << 16;
    return v.f;
}
__device__ __forceinline__ short f2bf_hw(float f) {  // v_cvt_pk_bf16_f32 (RNE)
    unsigned r;
    float z = 0.0f;
    asm("v_cvt_pk_bf16_f32 %0, %1, %2" : "=v"(r) : "v"(f), "v"(z));
    return (short)(r & 0xFFFFu);
}

// ---------------- Phase A: input projections, MFMA GEMM ----------------
// Block: 128 rows x 256 cols, 512 threads = 8 waves.
__global__ __launch_bounds__(512, 2) void lstm_phaseA(
    const int* __restrict__ x, const float* __restrict__ emb,
    const float* __restrict__ Wf, const float* __restrict__ bf,
    const float* __restrict__ Wc, const float* __restrict__ bc,
    float* __restrict__ pre, int t0, int t1, int S)
{
    __shared__ __align__(16) short a_hi[128][136];
    __shared__ __align__(16) short a_lo[128][136];
    __shared__ int idx_s[128];

    const int tid  = threadIdx.x;
    const int lane = tid & 63;
    const int w    = tid >> 6;
    const int r0   = blockIdx.x * 128;
    const int total_rows = (t1 - t0) * LSTM_B;
    const int nrows = (total_rows - r0 < 128) ? (total_rows - r0) : 128;

    if (tid < 128 && tid < nrows) {
        const int r = r0 + tid;
        idx_s[tid] = x[(size_t)(r & 63) * S + t0 + (r >> 6)];
    }
    __syncthreads();

    {   // gather emb rows -> bf16 hi/lo; 4 threads/row, staged, ds_write_b128
        const int row  = tid >> 2;
        const int part = (tid & 3) * 32;
        if (row < nrows) {
            const float* src = emb + (size_t)idx_s[row] * LSTM_E + part;
            bf16x8 vh[4], vl[4];
#pragma unroll
            for (int q = 0; q < 4; ++q) {
                float4 u = *(const float4*)(src + 8*q);
                float4 v = *(const float4*)(src + 8*q + 4);
                float e[8] = {u.x,u.y,u.z,u.w,v.x,v.y,v.z,v.w};
#pragma unroll
                for (int k = 0; k < 8; ++k) {
                    short h = f2bf(e[k]);
                    vh[q][k] = h;
                    vl[q][k] = f2bf(e[k] - bf2f(h));
                }
            }
#pragma unroll
            for (int q = 0; q < 4; ++q) {
                *(bf16x8*)&a_hi[row][part + 8*q] = vh[q];
                *(bf16x8*)&a_lo[row][part + 8*q] = vl[q];
            }
        }
    }

    // resident B-fragments: W E-part (cols 0..127), bf16
    const int jj = 16 * w + (lane & 15);
    const int kb = ((lane >> 4) & 3) * 8;
    bf16x8 bFr[4], bCr[4];
#pragma unroll
    for (int ks = 0; ks < 4; ++ks) {
        const float* rF = Wf + (size_t)jj * ROWW + 32*ks + kb;
        const float* rC = Wc + (size_t)jj * ROWW + 32*ks + kb;
        float4 f0 = *(const float4*)rF, f1 = *(const float4*)(rF + 4);
        float4 c0 = *(const float4*)rC, c1 = *(const float4*)(rC + 4);
        float ef[8] = {f0.x,f0.y,f0.z,f0.w,f1.x,f1.y,f1.z,f1.w};
        float ec[8] = {c0.x,c0.y,c0.z,c0.w,c1.x,c1.y,c1.z,c1.w};
#pragma unroll
        for (int e = 0; e < 8; ++e) { bFr[ks][e] = f2bf(ef[e]); bCr[ks][e] = f2bf(ec[e]); }
    }
    const float biasF = bf[jj], biasC = bc[jj];
    __syncthreads();

    f32x4 accF[8], accC[8];
#pragma unroll
    for (int m = 0; m < 8; ++m) {
        accF[m] = (f32x4){biasF, biasF, biasF, biasF};
        accC[m] = (f32x4){biasC, biasC, biasC, biasC};
    }

#pragma unroll
    for (int m = 0; m < 8; ++m) {
        const int ar = m * 16 + (lane & 15);
#pragma unroll
        for (int ks = 0; ks < 4; ++ks) {
            bf16x8 ah = *(const bf16x8*)&a_hi[ar][32*ks + kb];
            bf16x8 al = *(const bf16x8*)&a_lo[ar][32*ks + kb];
            accF[m] = __builtin_amdgcn_mfma_f32_16x16x32_bf16(ah, bFr[ks], accF[m], 0,0,0);
            accC[m] = __builtin_amdgcn_mfma_f32_16x16x32_bf16(ah, bCr[ks], accC[m], 0,0,0);
            accF[m] = __builtin_amdgcn_mfma_f32_16x16x32_bf16(al, bFr[ks], accF[m], 0,0,0);
            accC[m] = __builtin_amdgcn_mfma_f32_16x16x32_bf16(al, bCr[ks], accC[m], 0,0,0);
        }
    }

#pragma unroll
    for (int m = 0; m < 8; ++m) {
#pragma unroll
        for (int i = 0; i < 4; ++i) {
            const int rl = m * 16 + ((lane >> 4) & 3) * 4 + i;   // row in block
            if (rl < nrows) {
                const int r = r0 + rl;
                float* dst = pre + (size_t)(r >> 6) * TSTRIDE
                                 + (size_t)(r & 63) * LSTM_H + jj;
                dst[0]                 = accF[m][i];   // gate f plane
                dst[LSTM_B * LSTM_H]   = accC[m][i];   // gate c plane
            }
        }
    }
}

// ---------------- Phase B: the recurrence (MFMA), 2 batches/block ----------
// 32 blocks (batches 2k, 2k+1), 512 threads = 8 waves.
// Wave w, lane l: output j = 16*w + (l&15), both batches, shared weights.
__global__ __launch_bounds__(512, 2) void lstm_phaseB(
    const float* __restrict__ Wf, const float* __restrict__ Wc,
    const float* __restrict__ Wfc, const float* __restrict__ bfc,
    const float* __restrict__ pre, float* __restrict__ state,
    float* __restrict__ out, int t0, int t1, int S)
{
    __shared__ __align__(16) short h_s[2][2][LSTM_H];   // [buf][batch][j]
    __shared__ float red_s[2][LSTM_H];

    const int b0   = 2 * blockIdx.x;
    const int b1   = b0 + 1;
    const int tid  = threadIdx.x;
    const int lane = tid & 63;
    const int w    = tid >> 6;          // wave 0..7
    const int jj   = 16 * w + (lane & 15);
    const int kb   = ((lane >> 4) & 3) * 8;   // k-sub-base within a kstep

    // ---- resident B-fragments: W h-part, bf16 (shared by both batches) ----
    bf16x8 bF[4], bC[4];
#pragma unroll
    for (int ks = 0; ks < 4; ++ks) {
        const float* rF = Wf + (size_t)jj * ROWW + LSTM_E + 32*ks + kb;
        const float* rC = Wc + (size_t)jj * ROWW + LSTM_E + 32*ks + kb;
        float4 f0 = *(const float4*)rF, f1 = *(const float4*)(rF + 4);
        float4 c0 = *(const float4*)rC, c1 = *(const float4*)(rC + 4);
        float ef[8] = {f0.x,f0.y,f0.z,f0.w,f1.x,f1.y,f1.z,f1.w};
        float ec[8] = {c0.x,c0.y,c0.z,c0.w,c1.x,c1.y,c1.z,c1.w};
#pragma unroll
        for (int e = 0; e < 8; ++e) {
            bF[ks][e] = f2bf(ef[e]);
            bC[ks][e] = f2bf(ec[e]);
        }
    }

    float cA = 0.0f, cB = 0.0f, hlA = 0.0f, hlB = 0.0f;
    if (t0 == 0) {
        if (tid < 2 * LSTM_H) ((short*)h_s[0])[tid] = 0;
    } else {
        if (tid < 2 * LSTM_H) {
            const int bb = tid >> 7, j = tid & 127;
            h_s[0][bb][j] = f2bf(state[(size_t)(b0 + bb) * LSTM_H + j]);
        }
        cA = state[LSTM_B * LSTM_H + (size_t)b0 * LSTM_H + jj];
        cB = state[LSTM_B * LSTM_H + (size_t)b1 * LSTM_H + jj];
    }

    // pre streams, 2-deep prefetch; 2-body unroll, dedicated regs, 32-bit offs
    const float* prepFA = pre + (size_t)b0 * LSTM_H + jj;      // [t][g=0][b][j]
    const float* prepCA = prepFA + LSTM_B * LSTM_H;            // g=1
    const float* prepFB = pre + (size_t)b1 * LSTM_H + jj;
    const float* prepCB = prepFB + LSTM_B * LSTM_H;
    const int NT = t1 - t0;
    float pfA0 = prepFA[0], pcA0 = prepCA[0];
    float pfB0 = prepFB[0], pcB0 = prepCB[0];
    float pfA1 = 0.f, pcA1 = 0.f, pfB1 = 0.f, pcB1 = 0.f;
    if (NT > 1) {
        pfA1 = prepFA[TSTRIDE]; pcA1 = prepCA[TSTRIDE];
        pfB1 = prepFB[TSTRIDE]; pcB1 = prepCB[TSTRIDE];
    }
    int off0 = 2 * TSTRIDE;   // body0 refill: even steps t+2
    int off1 = 3 * TSTRIDE;   // body1 refill: odd steps t+3
    __syncthreads();

    const f32x4 zz = {0.f, 0.f, 0.f, 0.f};

    // One timestep, BOTH batches. 8 independent MFMAs then 8 dependent.
#define STEP_BODY(CUR, NXT, PFA, PCA, PFB, PCB, OFF, TLD)                       \
    do {                                                                        \
        const short* hbA = &h_s[CUR][0][0];                                     \
        const short* hbB = &h_s[CUR][1][0];                                     \
        bf16x8 a0A = *(const bf16x8*)(hbA + 0*32 + kb);                         \
        bf16x8 a1A = *(const bf16x8*)(hbA + 1*32 + kb);                         \
        bf16x8 a2A = *(const bf16x8*)(hbA + 2*32 + kb);                         \
        bf16x8 a3A = *(const bf16x8*)(hbA + 3*32 + kb);                         \
        bf16x8 a0B = *(const bf16x8*)(hbB + 0*32 + kb);                         \
        bf16x8 a1B = *(const bf16x8*)(hbB + 1*32 + kb);                         \
        bf16x8 a2B = *(const bf16x8*)(hbB + 2*32 + kb);                         \
        bf16x8 a3B = *(const bf16x8*)(hbB + 3*32 + kb);                         \
        float afinA = PFA, acinA = PCA, afinB = PFB, acinB = PCB;               \
        if ((TLD) < NT) {                                                       \
            PFA = prepFA[OFF]; PCA = prepCA[OFF];                               \
            PFB = prepFB[OFF]; PCB = prepCB[OFF];                               \
        }                                                                       \
        OFF += 2 * TSTRIDE;                                                     \
        f32x4 faA = __builtin_amdgcn_mfma_f32_16x16x32_bf16(a0A, bF[0], zz, 0,0,0);\
        f32x4 gaA = __builtin_amdgcn_mfma_f32_16x16x32_bf16(a0A, bC[0], zz, 0,0,0);\
        f32x4 faB = __builtin_amdgcn_mfma_f32_16x16x32_bf16(a0B, bF[0], zz, 0,0,0);\
        f32x4 gaB = __builtin_amdgcn_mfma_f32_16x16x32_bf16(a0B, bC[0], zz, 0,0,0);\
        f32x4 fbA = __builtin_amdgcn_mfma_f32_16x16x32_bf16(a2A, bF[2], zz, 0,0,0);\
        f32x4 gbA = __builtin_amdgcn_mfma_f32_16x16x32_bf16(a2A, bC[2], zz, 0,0,0);\
        f32x4 fbB = __builtin_amdgcn_mfma_f32_16x16x32_bf16(a2B, bF[2], zz, 0,0,0);\
        f32x4 gbB = __builtin_amdgcn_mfma_f32_16x16x32_bf16(a2B, bC[2], zz, 0,0,0);\
        faA = __builtin_amdgcn_mfma_f32_16x16x32_bf16(a1A, bF[1], faA, 0,0,0);  \
        gaA = __builtin_amdgcn_mfma_f32_16x16x32_bf16(a1A, bC[1], gaA, 0,0,0);  \
        faB = __builtin_amdgcn_mfma_f32_16x16x32_bf16(a1B, bF[1], faB, 0,0,0);  \
        gaB = __builtin_amdgcn_mfma_f32_16x16x32_bf16(a1B, bC[1], gaB, 0,0,0);  \
        fbA = __builtin_amdgcn_mfma_f32_16x16x32_bf16(a3A, bF[3], fbA, 0,0,0);  \
        gbA = __builtin_amdgcn_mfma_f32_16x16x32_bf16(a3A, bC[3], gbA, 0,0,0);  \
        fbB = __builtin_amdgcn_mfma_f32_16x16x32_bf16(a3B, bF[3], fbB, 0,0,0);  \
        gbB = __builtin_amdgcn_mfma_f32_16x16x32_bf16(a3B, bC[3], gbB, 0,0,0);  \
        float afA = afinA + (faA[0] + fbA[0]);                                  \
        float acA = acinA + (gaA[0] + gbA[0]);                                  \
        float afB = afinB + (faB[0] + fbB[0]);                                  \
        float acB = acinB + (gaB[0] + gbB[0]);                                  \
        float ggA = sigmoidf_(afA);                                             \
        float ctA = tanh_fast(acA);                                             \
        float ggB = sigmoidf_(afB);                                             \
        float ctB = tanh_fast(acB);                                             \
        cA = ggA * (cA + ctA);                                                  \
        cB = ggB * (cB + ctB);                                                  \
        float hnA = ggA * tanh_fast(cA);                                        \
        float hnB = ggB * tanh_fast(cB);                                        \
        hlA = hnA; hlB = hnB;                                                   \
        if (lane < 16) {                                                        \
            h_s[NXT][0][jj] = f2bf_hw(hnA);                                     \
            h_s[NXT][1][jj] = f2bf_hw(hnB);                                     \
        }                                                                       \
        __syncthreads();                                                        \
    } while (0)

    int t = 0;
    for (; t + 1 < NT; t += 2) {
        STEP_BODY(0, 1, pfA0, pcA0, pfB0, pcB0, off0, t + 2);
        STEP_BODY(1, 0, pfA1, pcA1, pfB1, pcB1, off1, t + 3);
    }
    if (t < NT) { STEP_BODY(0, 1, pfA0, pcA0, pfB0, pcB0, off0, t + 2); }
#undef STEP_BODY

    if (t1 == S) {
        if (lane < 16) {
            red_s[0][jj] = hlA * Wfc[jj];
            red_s[1][jj] = hlB * Wfc[jj];
        }
        __syncthreads();
        if (tid < 128) {
            const int bb = tid >> 6;   // 0 or 1
            const int i  = tid & 63;
            float s = red_s[bb][i] + red_s[bb][i + 64];
            s += __shfl_down(s, 32, 64);
            s += __shfl_down(s, 16, 64);
            s += __shfl_down(s, 8, 64);
            s += __shfl_down(s, 4, 64);
            s += __shfl_down(s, 2, 64);
            s += __shfl_down(s, 1, 64);
            if (i == 0) out[b0 + bb] = sigmoidf_(s + bfc[0]);
        }
    } else {
        if (lane < 16) {
            state[(size_t)b0 * LSTM_H + jj] = hlA;
            state[(size_t)b1 * LSTM_H + jj] = hlB;
            state[LSTM_B * LSTM_H + (size_t)b0 * LSTM_H + jj] = cA;
            state[LSTM_B * LSTM_H + (size_t)b1 * LSTM_H + jj] = cB;
        }
    }
}

extern "C" void kernel_launch(void* const* d_in, const int* in_sizes, int n_in,
                              void* d_out, int out_size, void* d_ws, size_t ws_size,
                              hipStream_t stream) {
    const int*   x   = (const int*)d_in[0];
    const float* emb = (const float*)d_in[1];
    const float* Wf  = (const float*)d_in[2];
    const float* bf  = (const float*)d_in[3];
    const float* Wc  = (const float*)d_in[4];
    const float* bc  = (const float*)d_in[5];
    const float* Wfc = (const float*)d_in[6];
    const float* bfc = (const float*)d_in[7];
    float* out = (float*)d_out;

    const int S = in_sizes[0] / LSTM_B;           // 2048

    float* state = (float*)d_ws;                              // h[64][128], c[64][128]
    float* pre   = state + (size_t)2 * LSTM_B * LSTM_H;       // + 64KB

    const size_t state_bytes = (size_t)2 * LSTM_B * LSTM_H * sizeof(float);
    const size_t per_t_bytes = (size_t)TSTRIDE * sizeof(float);   // 64 KB per step
    size_t avail = (ws_size > state_bytes) ? (ws_size - state_bytes) : 0;
    int CH = (int)(avail / per_t_bytes);
    if (CH > S) CH = S;
    if (CH < 1) CH = 1;   // requires ws_size >= 128KB + state

    for (int t0 = 0; t0 < S; t0 += CH) {
        const int t1 = (t0 + CH < S) ? (t0 + CH) : S;
        const int nblocksA = ((t1 - t0) * LSTM_B + 127) / 128;
        lstm_phaseA<<<nblocksA, 512, 0, stream>>>(x, emb, Wf, bf, Wc, bc,
                                                  pre, t0, t1, S);
        lstm_phaseB<<<LSTM_B / 2, 512, 0, stream>>>(Wf, Wc, Wfc, bfc, pre, state,
                                                    out, t0, t1, S);
    }
}

// Round 12
// 1281.721 us; speedup vs baseline: 1.1430x; 1.1430x over previous
//
#include <hip/hip_runtime.h>
#include <hip/hip_bf16.h>

// LSTM classifier: B=64, S=2048, E=H=128, OUT=1.
// Phase A (parallel, MFMA GEMM): pre[t][g][b][j] = bias + emb[x[b,t]].W_g[j][:128]
// Phase B round-12: 2 batches/block with HALF-STEP PHASE OFFSET.
//   r11 failed because one barrier kept both batches' MFMA/tail phases
//   time-aligned (lockstep) -> serial chains concatenated. Now 2 barriers per
//   iteration: half-1 = {read A-frags, tail_B(t-1), write h_B, MFMA_A(t)},
//   half-2 = {read B-frags, tail_A(t), write h_A, MFMA_B(t)}. One batch's
//   tail (~170 cyc VALU) hides under the other batch's 310-cyc matrix drain.
//   MFMA results cross barriers in registers; lds_only_barrier (r10, proven)
//   keeps prefetch loads in flight.

#define LSTM_B 64
#define LSTM_E 128
#define LSTM_H 128
#define ROWW   256           // E+H, weight row width
#define TSTRIDE (2*LSTM_B*LSTM_H)   // floats per timestep in pre buffer

typedef __attribute__((ext_vector_type(8))) short bf16x8;
typedef __attribute__((ext_vector_type(4))) float f32x4;

__device__ __forceinline__ float fast_rcp(float x) {
    return __builtin_amdgcn_rcpf(x);
}
__device__ __forceinline__ float sigmoidf_(float x) {
    return fast_rcp(1.0f + __expf(-x));
}
__device__ __forceinline__ float tanh_fast(float x) {
    float ax = fabsf(x);
    float t = __expf(-2.0f * ax);          // in (0,1], no overflow
    float r = (1.0f - t) * fast_rcp(1.0f + t);
    return copysignf(r, x);
}
__device__ __forceinline__ short f2bf(float f) {   // round-to-nearest-even
    union { float f; unsigned u; } v; v.f = f;
    unsigned r = (v.u + 0x7FFFu + ((v.u >> 16) & 1u)) >> 16;
    return (short)r;
}
__device__ __forceinline__ float bf2f(short s) {
    union { unsigned u; float f; } v; v.u = ((unsigned)(unsigned short)s) << 16;
    return v.f;
}
__device__ __forceinline__ short f2bf_hw(float f) {  // v_cvt_pk_bf16_f32 (RNE)
    unsigned r;
    float z = 0.0f;
    asm("v_cvt_pk_bf16_f32 %0, %1, %2" : "=v"(r) : "v"(f), "v"(z));
    return (short)(r & 0xFFFFu);
}

// Barrier waiting only on LDS ops; vmcnt/expcnt untouched (prefetch stays in
// flight). simm16: vmcnt=63, expcnt=7, lgkmcnt=0 -> 0xC07F. (r10: correct,
// neutral there; here the halves are short enough that the drain would hurt.)
__device__ __forceinline__ void lds_only_barrier() {
    __builtin_amdgcn_s_waitcnt(0xC07F);
    __builtin_amdgcn_s_barrier();
}

// ---------------- Phase A: input projections, MFMA GEMM (unchanged) --------
__global__ __launch_bounds__(512, 2) void lstm_phaseA(
    const int* __restrict__ x, const float* __restrict__ emb,
    const float* __restrict__ Wf, const float* __restrict__ bf,
    const float* __restrict__ Wc, const float* __restrict__ bc,
    float* __restrict__ pre, int t0, int t1, int S)
{
    __shared__ __align__(16) short a_hi[128][136];
    __shared__ __align__(16) short a_lo[128][136];
    __shared__ int idx_s[128];

    const int tid  = threadIdx.x;
    const int lane = tid & 63;
    const int w    = tid >> 6;
    const int r0   = blockIdx.x * 128;
    const int total_rows = (t1 - t0) * LSTM_B;
    const int nrows = (total_rows - r0 < 128) ? (total_rows - r0) : 128;

    if (tid < 128 && tid < nrows) {
        const int r = r0 + tid;
        idx_s[tid] = x[(size_t)(r & 63) * S + t0 + (r >> 6)];
    }
    __syncthreads();

    {   // gather emb rows -> bf16 hi/lo; 4 threads/row, staged, ds_write_b128
        const int row  = tid >> 2;
        const int part = (tid & 3) * 32;
        if (row < nrows) {
            const float* src = emb + (size_t)idx_s[row] * LSTM_E + part;
            bf16x8 vh[4], vl[4];
#pragma unroll
            for (int q = 0; q < 4; ++q) {
                float4 u = *(const float4*)(src + 8*q);
                float4 v = *(const float4*)(src + 8*q + 4);
                float e[8] = {u.x,u.y,u.z,u.w,v.x,v.y,v.z,v.w};
#pragma unroll
                for (int k = 0; k < 8; ++k) {
                    short h = f2bf(e[k]);
                    vh[q][k] = h;
                    vl[q][k] = f2bf(e[k] - bf2f(h));
                }
            }
#pragma unroll
            for (int q = 0; q < 4; ++q) {
                *(bf16x8*)&a_hi[row][part + 8*q] = vh[q];
                *(bf16x8*)&a_lo[row][part + 8*q] = vl[q];
            }
        }
    }

    // resident B-fragments: W E-part (cols 0..127), bf16
    const int jj = 16 * w + (lane & 15);
    const int kb = ((lane >> 4) & 3) * 8;
    bf16x8 bFr[4], bCr[4];
#pragma unroll
    for (int ks = 0; ks < 4; ++ks) {
        const float* rF = Wf + (size_t)jj * ROWW + 32*ks + kb;
        const float* rC = Wc + (size_t)jj * ROWW + 32*ks + kb;
        float4 f0 = *(const float4*)rF, f1 = *(const float4*)(rF + 4);
        float4 c0 = *(const float4*)rC, c1 = *(const float4*)(rC + 4);
        float ef[8] = {f0.x,f0.y,f0.z,f0.w,f1.x,f1.y,f1.z,f1.w};
        float ec[8] = {c0.x,c0.y,c0.z,c0.w,c1.x,c1.y,c1.z,c1.w};
#pragma unroll
        for (int e = 0; e < 8; ++e) { bFr[ks][e] = f2bf(ef[e]); bCr[ks][e] = f2bf(ec[e]); }
    }
    const float biasF = bf[jj], biasC = bc[jj];
    __syncthreads();

    f32x4 accF[8], accC[8];
#pragma unroll
    for (int m = 0; m < 8; ++m) {
        accF[m] = (f32x4){biasF, biasF, biasF, biasF};
        accC[m] = (f32x4){biasC, biasC, biasC, biasC};
    }

#pragma unroll
    for (int m = 0; m < 8; ++m) {
        const int ar = m * 16 + (lane & 15);
#pragma unroll
        for (int ks = 0; ks < 4; ++ks) {
            bf16x8 ah = *(const bf16x8*)&a_hi[ar][32*ks + kb];
            bf16x8 al = *(const bf16x8*)&a_lo[ar][32*ks + kb];
            accF[m] = __builtin_amdgcn_mfma_f32_16x16x32_bf16(ah, bFr[ks], accF[m], 0,0,0);
            accC[m] = __builtin_amdgcn_mfma_f32_16x16x32_bf16(ah, bCr[ks], accC[m], 0,0,0);
            accF[m] = __builtin_amdgcn_mfma_f32_16x16x32_bf16(al, bFr[ks], accF[m], 0,0,0);
            accC[m] = __builtin_amdgcn_mfma_f32_16x16x32_bf16(al, bCr[ks], accC[m], 0,0,0);
        }
    }

#pragma unroll
    for (int m = 0; m < 8; ++m) {
#pragma unroll
        for (int i = 0; i < 4; ++i) {
            const int rl = m * 16 + ((lane >> 4) & 3) * 4 + i;   // row in block
            if (rl < nrows) {
                const int r = r0 + rl;
                float* dst = pre + (size_t)(r >> 6) * TSTRIDE
                                 + (size_t)(r & 63) * LSTM_H + jj;
                dst[0]                 = accF[m][i];   // gate f plane
                dst[LSTM_B * LSTM_H]   = accC[m][i];   // gate c plane
            }
        }
    }
}

// ---------------- Phase B: 2 batches/block, half-step phase offset ----------
// 32 blocks, 512 threads = 8 waves. Wave w, lane l: j = 16*w + (l&15).
__global__ __launch_bounds__(512, 2) void lstm_phaseB(
    const float* __restrict__ Wf, const float* __restrict__ Wc,
    const float* __restrict__ Wfc, const float* __restrict__ bfc,
    const float* __restrict__ pre, float* __restrict__ state,
    float* __restrict__ out, int t0, int t1, int S)
{
    __shared__ __align__(16) short h_s[2][2][LSTM_H];   // [batch][buf][j]
    __shared__ float red_s[2][LSTM_H];

    const int b0   = 2 * blockIdx.x;
    const int b1   = b0 + 1;
    const int tid  = threadIdx.x;
    const int lane = tid & 63;
    const int w    = tid >> 6;          // wave 0..7
    const int jj   = 16 * w + (lane & 15);
    const int kb   = ((lane >> 4) & 3) * 8;   // k-sub-base within a kstep

    // ---- resident B-fragments: W h-part, bf16 (shared by both batches) ----
    bf16x8 bF[4], bC[4];
#pragma unroll
    for (int ks = 0; ks < 4; ++ks) {
        const float* rF = Wf + (size_t)jj * ROWW + LSTM_E + 32*ks + kb;
        const float* rC = Wc + (size_t)jj * ROWW + LSTM_E + 32*ks + kb;
        float4 f0 = *(const float4*)rF, f1 = *(const float4*)(rF + 4);
        float4 c0 = *(const float4*)rC, c1 = *(const float4*)(rC + 4);
        float ef[8] = {f0.x,f0.y,f0.z,f0.w,f1.x,f1.y,f1.z,f1.w};
        float ec[8] = {c0.x,c0.y,c0.z,c0.w,c1.x,c1.y,c1.z,c1.w};
#pragma unroll
        for (int e = 0; e < 8; ++e) {
            bF[ks][e] = f2bf(ef[e]);
            bC[ks][e] = f2bf(ec[e]);
        }
    }

    float cA = 0.0f, cB = 0.0f, hlA = 0.0f, hlB = 0.0f;
    if (t0 == 0) {
        if (tid < 2 * LSTM_H) {
            const int bb = tid >> 7, j = tid & 127;
            h_s[bb][0][j] = 0;
        }
    } else {
        if (tid < 2 * LSTM_H) {
            const int bb = tid >> 7, j = tid & 127;
            h_s[bb][0][j] = f2bf(state[(size_t)(b0 + bb) * LSTM_H + j]);
        }
        cA = state[LSTM_B * LSTM_H + (size_t)b0 * LSTM_H + jj];
        cB = state[LSTM_B * LSTM_H + (size_t)b1 * LSTM_H + jj];
    }

    const float* prepFA = pre + (size_t)b0 * LSTM_H + jj;      // [t][g=0][b][j]
    const float* prepCA = prepFA + LSTM_B * LSTM_H;            // g=1
    const float* prepFB = pre + (size_t)b1 * LSTM_H + jj;
    const float* prepCB = prepFB + LSTM_B * LSTM_H;
    const int NT = t1 - t0;
    float pfA0 = prepFA[0], pcA0 = prepCA[0];
    float pfB0 = prepFB[0], pcB0 = prepCB[0];
    float pfA1 = 0.f, pcA1 = 0.f, pfB1 = 0.f, pcB1 = 0.f;
    if (NT > 1) {
        pfA1 = prepFA[TSTRIDE]; pcA1 = prepCA[TSTRIDE];
        pfB1 = prepFB[TSTRIDE]; pcB1 = prepCB[TSTRIDE];
    }
    int offA = 2 * TSTRIDE;   // next A-load: step 2
    int offB = 2 * TSTRIDE;   // next B-load: step 2
    __syncthreads();          // h init visible (full drain once, harmless)

    const f32x4 zz = {0.f, 0.f, 0.f, 0.f};
    f32x4 mfAf = zz, mfAc = zz, mfBf = zz, mfBc = zz;

    // HALF1(RD, T): {read A-frags h_A[T], tail_B(T-1) -> write h_B[T],
    //                MFMA_A(T)} ; barrier.
#define HALF1(RD, T, DO_TAILB)                                                  \
    do {                                                                        \
        const short* hA_ = &h_s[0][RD][0];                                      \
        bf16x8 a0 = *(const bf16x8*)(hA_ + 0*32 + kb);                          \
        bf16x8 a1 = *(const bf16x8*)(hA_ + 1*32 + kb);                          \
        bf16x8 a2 = *(const bf16x8*)(hA_ + 2*32 + kb);                          \
        bf16x8 a3 = *(const bf16x8*)(hA_ + 3*32 + kb);                          \
        if (DO_TAILB) {                                                         \
            float afB = pfB0 + mfBf[0];                                         \
            float acB = pcB0 + mfBc[0];                                         \
            pfB0 = pfB1; pcB0 = pcB1;                                           \
            if ((T) + 1 < NT) { pfB1 = prepFB[offB]; pcB1 = prepCB[offB]; }     \
            offB += TSTRIDE;                                                    \
            float ggB = sigmoidf_(afB);                                         \
            float ctB = tanh_fast(acB);                                         \
            cB = ggB * (cB + ctB);                                              \
            float hnB = ggB * tanh_fast(cB);                                    \
            hlB = hnB;                                                          \
            if (lane < 16) h_s[1][RD][jj] = f2bf_hw(hnB);                       \
        }                                                                       \
        f32x4 tf = __builtin_amdgcn_mfma_f32_16x16x32_bf16(a0, bF[0], zz, 0,0,0);\
        f32x4 tc = __builtin_amdgcn_mfma_f32_16x16x32_bf16(a0, bC[0], zz, 0,0,0);\
        tf = __builtin_amdgcn_mfma_f32_16x16x32_bf16(a1, bF[1], tf, 0,0,0);     \
        tc = __builtin_amdgcn_mfma_f32_16x16x32_bf16(a1, bC[1], tc, 0,0,0);     \
        tf = __builtin_amdgcn_mfma_f32_16x16x32_bf16(a2, bF[2], tf, 0,0,0);     \
        tc = __builtin_amdgcn_mfma_f32_16x16x32_bf16(a2, bC[2], tc, 0,0,0);     \
        tf = __builtin_amdgcn_mfma_f32_16x16x32_bf16(a3, bF[3], tf, 0,0,0);     \
        tc = __builtin_amdgcn_mfma_f32_16x16x32_bf16(a3, bC[3], tc, 0,0,0);     \
        mfAf = tf; mfAc = tc;                                                   \
        lds_only_barrier();                                                     \
    } while (0)

    // HALF2(RD, WR, T): {read B-frags h_B[T], tail_A(T) -> write h_A[T+1],
    //                    MFMA_B(T)} ; barrier.
#define HALF2(RD, WR, T)                                                        \
    do {                                                                        \
        const short* hB_ = &h_s[1][RD][0];                                      \
        bf16x8 a0 = *(const bf16x8*)(hB_ + 0*32 + kb);                          \
        bf16x8 a1 = *(const bf16x8*)(hB_ + 1*32 + kb);                          \
        bf16x8 a2 = *(const bf16x8*)(hB_ + 2*32 + kb);                          \
        bf16x8 a3 = *(const bf16x8*)(hB_ + 3*32 + kb);                          \
        {                                                                       \
            float afA = pfA0 + mfAf[0];                                         \
            float acA = pcA0 + mfAc[0];                                         \
            pfA0 = pfA1; pcA0 = pcA1;                                           \
            if ((T) + 2 < NT) { pfA1 = prepFA[offA]; pcA1 = prepCA[offA]; }     \
            offA += TSTRIDE;                                                    \
            float ggA = sigmoidf_(afA);                                         \
            float ctA = tanh_fast(acA);                                         \
            cA = ggA * (cA + ctA);                                              \
            float hnA = ggA * tanh_fast(cA);                                    \
            hlA = hnA;                                                          \
            if (lane < 16) h_s[0][WR][jj] = f2bf_hw(hnA);                       \
        }                                                                       \
        f32x4 tf = __builtin_amdgcn_mfma_f32_16x16x32_bf16(a0, bF[0], zz, 0,0,0);\
        f32x4 tc = __builtin_amdgcn_mfma_f32_16x16x32_bf16(a0, bC[0], zz, 0,0,0);\
        tf = __builtin_amdgcn_mfma_f32_16x16x32_bf16(a1, bF[1], tf, 0,0,0);     \
        tc = __builtin_amdgcn_mfma_f32_16x16x32_bf16(a1, bC[1], tc, 0,0,0);     \
        tf = __builtin_amdgcn_mfma_f32_16x16x32_bf16(a2, bF[2], tf, 0,0,0);     \
        tc = __builtin_amdgcn_mfma_f32_16x16x32_bf16(a2, bC[2], tc, 0,0,0);     \
        tf = __builtin_amdgcn_mfma_f32_16x16x32_bf16(a3, bF[3], tf, 0,0,0);     \
        tc = __builtin_amdgcn_mfma_f32_16x16x32_bf16(a3, bC[3], tc, 0,0,0);     \
        mfBf = tf; mfBc = tc;                                                   \
        lds_only_barrier();                                                     \
    } while (0)

    // iteration 0 (buffers: read 0, write 1); no tail_B yet
    HALF1(0, 0, 0);
    HALF2(0, 1, 0);
    int t = 1;
    for (; t + 1 < NT; t += 2) {
        HALF1(1, t, 1);     HALF2(1, 0, t);
        HALF1(0, t + 1, 1); HALF2(0, 1, t + 1);
    }
    if (t < NT) { HALF1(1, t, 1); HALF2(1, 0, t); }
#undef HALF1
#undef HALF2

    // epilogue: tail_B(NT-1)
    {
        float afB = pfB0 + mfBf[0];
        float acB = pcB0 + mfBc[0];
        float ggB = sigmoidf_(afB);
        float ctB = tanh_fast(acB);
        cB = ggB * (cB + ctB);
        hlB = ggB * tanh_fast(cB);
    }

    if (t1 == S) {
        if (lane < 16) {
            red_s[0][jj] = hlA * Wfc[jj];
            red_s[1][jj] = hlB * Wfc[jj];
        }
        __syncthreads();
        if (tid < 128) {
            const int bb = tid >> 6;   // 0 or 1
            const int i  = tid & 63;
            float s = red_s[bb][i] + red_s[bb][i + 64];
            s += __shfl_down(s, 32, 64);
            s += __shfl_down(s, 16, 64);
            s += __shfl_down(s, 8, 64);
            s += __shfl_down(s, 4, 64);
            s += __shfl_down(s, 2, 64);
            s += __shfl_down(s, 1, 64);
            if (i == 0) out[b0 + bb] = sigmoidf_(s + bfc[0]);
        }
    } else {
        if (lane < 16) {
            state[(size_t)b0 * LSTM_H + jj] = hlA;
            state[(size_t)b1 * LSTM_H + jj] = hlB;
            state[LSTM_B * LSTM_H + (size_t)b0 * LSTM_H + jj] = cA;
            state[LSTM_B * LSTM_H + (size_t)b1 * LSTM_H + jj] = cB;
        }
    }
}

extern "C" void kernel_launch(void* const* d_in, const int* in_sizes, int n_in,
                              void* d_out, int out_size, void* d_ws, size_t ws_size,
                              hipStream_t stream) {
    const int*   x   = (const int*)d_in[0];
    const float* emb = (const float*)d_in[1];
    const float* Wf  = (const float*)d_in[2];
    const float* bf  = (const float*)d_in[3];
    const float* Wc  = (const float*)d_in[4];
    const float* bc  = (const float*)d_in[5];
    const float* Wfc = (const float*)d_in[6];
    const float* bfc = (const float*)d_in[7];
    float* out = (float*)d_out;

    const int S = in_sizes[0] / LSTM_B;           // 2048

    float* state = (float*)d_ws;                              // h[64][128], c[64][128]
    float* pre   = state + (size_t)2 * LSTM_B * LSTM_H;       // + 64KB

    const size_t state_bytes = (size_t)2 * LSTM_B * LSTM_H * sizeof(float);
    const size_t per_t_bytes = (size_t)TSTRIDE * sizeof(float);   // 64 KB per step
    size_t avail = (ws_size > state_bytes) ? (ws_size - state_bytes) : 0;
    int CH = (int)(avail / per_t_bytes);
    if (CH > S) CH = S;
    if (CH < 1) CH = 1;   // requires ws_size >= 128KB + state

    for (int t0 = 0; t0 < S; t0 += CH) {
        const int t1 = (t0 + CH < S) ? (t0 + CH) : S;
        const int nblocksA = ((t1 - t0) * LSTM_B + 127) / 128;
        lstm_phaseA<<<nblocksA, 512, 0, stream>>>(x, emb, Wf, bf, Wc, bc,
                                                  pre, t0, t1, S);
        lstm_phaseB<<<LSTM_B / 2, 512, 0, stream>>>(Wf, Wc, Wfc, bfc, pre, state,
                                                    out, t0, t1, S);
    }
}

// Round 13
// 1264.608 us; speedup vs baseline: 1.1585x; 1.0135x over previous
//
#include <hip/hip_runtime.h>
#include <hip/hip_bf16.h>

// LSTM classifier: B=64, S=2048, E=H=128, OUT=1.
// Phase A (parallel, MFMA GEMM): pre[t][g][b][j] = bias + emb[x[b,t]].W_g[j][:128]
// Phase B round-13: r12's half-step phase-offset schedule + ANTI-REMAT PINS.
//   r12 regressed with VGPR=52: the allocator re-sank the weight-fragment
//   load+convert chains into the loop (r1 pathology), so the schedule never
//   ran with resident weights. Fix: pin the 8 bf16x8 fragments (32 VGPRs)
//   with an empty asm "+v" after conversion -- asm-defined values are not
//   rematerializable. r2's pin failed because it pinned 128 VGPRs of fp32
//   weights at 1 wave/SIMD; here it's the same 32 VGPRs r4-r10 held naturally.

#define LSTM_B 64
#define LSTM_E 128
#define LSTM_H 128
#define ROWW   256           // E+H, weight row width
#define TSTRIDE (2*LSTM_B*LSTM_H)   // floats per timestep in pre buffer

typedef __attribute__((ext_vector_type(8))) short bf16x8;
typedef __attribute__((ext_vector_type(4))) float f32x4;

__device__ __forceinline__ float fast_rcp(float x) {
    return __builtin_amdgcn_rcpf(x);
}
__device__ __forceinline__ float sigmoidf_(float x) {
    return fast_rcp(1.0f + __expf(-x));
}
__device__ __forceinline__ float tanh_fast(float x) {
    float ax = fabsf(x);
    float t = __expf(-2.0f * ax);          // in (0,1], no overflow
    float r = (1.0f - t) * fast_rcp(1.0f + t);
    return copysignf(r, x);
}
__device__ __forceinline__ short f2bf(float f) {   // round-to-nearest-even
    union { float f; unsigned u; } v; v.f = f;
    unsigned r = (v.u + 0x7FFFu + ((v.u >> 16) & 1u)) >> 16;
    return (short)r;
}
__device__ __forceinline__ float bf2f(short s) {
    union { unsigned u; float f; } v; v.u = ((unsigned)(unsigned short)s) << 16;
    return v.f;
}
__device__ __forceinline__ short f2bf_hw(float f) {  // v_cvt_pk_bf16_f32 (RNE)
    unsigned r;
    float z = 0.0f;
    asm("v_cvt_pk_bf16_f32 %0, %1, %2" : "=v"(r) : "v"(f), "v"(z));
    return (short)(r & 0xFFFFu);
}

// Pin a bf16x8 fragment in VGPRs: empty asm makes it asm-defined ->
// non-rematerializable -> allocator cannot re-sink the load+convert chain.
__device__ __forceinline__ void pin_frag(bf16x8& frag) {
    f32x4 t = __builtin_bit_cast(f32x4, frag);
    asm volatile("" : "+v"(t));
    frag = __builtin_bit_cast(bf16x8, t);
}

// Barrier waiting only on LDS ops; vmcnt untouched (prefetch stays in flight).
// simm16: vmcnt=63, expcnt=7, lgkmcnt=0 -> 0xC07F. (r10: proven correct.)
__device__ __forceinline__ void lds_only_barrier() {
    __builtin_amdgcn_s_waitcnt(0xC07F);
    __builtin_amdgcn_s_barrier();
}

// ---------------- Phase A: input projections, MFMA GEMM (unchanged) --------
__global__ __launch_bounds__(512, 2) void lstm_phaseA(
    const int* __restrict__ x, const float* __restrict__ emb,
    const float* __restrict__ Wf, const float* __restrict__ bf,
    const float* __restrict__ Wc, const float* __restrict__ bc,
    float* __restrict__ pre, int t0, int t1, int S)
{
    __shared__ __align__(16) short a_hi[128][136];
    __shared__ __align__(16) short a_lo[128][136];
    __shared__ int idx_s[128];

    const int tid  = threadIdx.x;
    const int lane = tid & 63;
    const int w    = tid >> 6;
    const int r0   = blockIdx.x * 128;
    const int total_rows = (t1 - t0) * LSTM_B;
    const int nrows = (total_rows - r0 < 128) ? (total_rows - r0) : 128;

    if (tid < 128 && tid < nrows) {
        const int r = r0 + tid;
        idx_s[tid] = x[(size_t)(r & 63) * S + t0 + (r >> 6)];
    }
    __syncthreads();

    {   // gather emb rows -> bf16 hi/lo; 4 threads/row, staged, ds_write_b128
        const int row  = tid >> 2;
        const int part = (tid & 3) * 32;
        if (row < nrows) {
            const float* src = emb + (size_t)idx_s[row] * LSTM_E + part;
            bf16x8 vh[4], vl[4];
#pragma unroll
            for (int q = 0; q < 4; ++q) {
                float4 u = *(const float4*)(src + 8*q);
                float4 v = *(const float4*)(src + 8*q + 4);
                float e[8] = {u.x,u.y,u.z,u.w,v.x,v.y,v.z,v.w};
#pragma unroll
                for (int k = 0; k < 8; ++k) {
                    short h = f2bf(e[k]);
                    vh[q][k] = h;
                    vl[q][k] = f2bf(e[k] - bf2f(h));
                }
            }
#pragma unroll
            for (int q = 0; q < 4; ++q) {
                *(bf16x8*)&a_hi[row][part + 8*q] = vh[q];
                *(bf16x8*)&a_lo[row][part + 8*q] = vl[q];
            }
        }
    }

    // resident B-fragments: W E-part (cols 0..127), bf16
    const int jj = 16 * w + (lane & 15);
    const int kb = ((lane >> 4) & 3) * 8;
    bf16x8 bFr[4], bCr[4];
#pragma unroll
    for (int ks = 0; ks < 4; ++ks) {
        const float* rF = Wf + (size_t)jj * ROWW + 32*ks + kb;
        const float* rC = Wc + (size_t)jj * ROWW + 32*ks + kb;
        float4 f0 = *(const float4*)rF, f1 = *(const float4*)(rF + 4);
        float4 c0 = *(const float4*)rC, c1 = *(const float4*)(rC + 4);
        float ef[8] = {f0.x,f0.y,f0.z,f0.w,f1.x,f1.y,f1.z,f1.w};
        float ec[8] = {c0.x,c0.y,c0.z,c0.w,c1.x,c1.y,c1.z,c1.w};
#pragma unroll
        for (int e = 0; e < 8; ++e) { bFr[ks][e] = f2bf(ef[e]); bCr[ks][e] = f2bf(ec[e]); }
    }
    const float biasF = bf[jj], biasC = bc[jj];
    __syncthreads();

    f32x4 accF[8], accC[8];
#pragma unroll
    for (int m = 0; m < 8; ++m) {
        accF[m] = (f32x4){biasF, biasF, biasF, biasF};
        accC[m] = (f32x4){biasC, biasC, biasC, biasC};
    }

#pragma unroll
    for (int m = 0; m < 8; ++m) {
        const int ar = m * 16 + (lane & 15);
#pragma unroll
        for (int ks = 0; ks < 4; ++ks) {
            bf16x8 ah = *(const bf16x8*)&a_hi[ar][32*ks + kb];
            bf16x8 al = *(const bf16x8*)&a_lo[ar][32*ks + kb];
            accF[m] = __builtin_amdgcn_mfma_f32_16x16x32_bf16(ah, bFr[ks], accF[m], 0,0,0);
            accC[m] = __builtin_amdgcn_mfma_f32_16x16x32_bf16(ah, bCr[ks], accC[m], 0,0,0);
            accF[m] = __builtin_amdgcn_mfma_f32_16x16x32_bf16(al, bFr[ks], accF[m], 0,0,0);
            accC[m] = __builtin_amdgcn_mfma_f32_16x16x32_bf16(al, bCr[ks], accC[m], 0,0,0);
        }
    }

#pragma unroll
    for (int m = 0; m < 8; ++m) {
#pragma unroll
        for (int i = 0; i < 4; ++i) {
            const int rl = m * 16 + ((lane >> 4) & 3) * 4 + i;   // row in block
            if (rl < nrows) {
                const int r = r0 + rl;
                float* dst = pre + (size_t)(r >> 6) * TSTRIDE
                                 + (size_t)(r & 63) * LSTM_H + jj;
                dst[0]                 = accF[m][i];   // gate f plane
                dst[LSTM_B * LSTM_H]   = accC[m][i];   // gate c plane
            }
        }
    }
}

// ---------------- Phase B: 2 batches/block, half-step phase offset ----------
// 32 blocks, 512 threads = 8 waves. Wave w, lane l: j = 16*w + (l&15).
__global__ __launch_bounds__(512, 2) void lstm_phaseB(
    const float* __restrict__ Wf, const float* __restrict__ Wc,
    const float* __restrict__ Wfc, const float* __restrict__ bfc,
    const float* __restrict__ pre, float* __restrict__ state,
    float* __restrict__ out, int t0, int t1, int S)
{
    __shared__ __align__(16) short h_s[2][2][LSTM_H];   // [batch][buf][j]
    __shared__ float red_s[2][LSTM_H];

    const int b0   = 2 * blockIdx.x;
    const int b1   = b0 + 1;
    const int tid  = threadIdx.x;
    const int lane = tid & 63;
    const int w    = tid >> 6;          // wave 0..7
    const int jj   = 16 * w + (lane & 15);
    const int kb   = ((lane >> 4) & 3) * 8;   // k-sub-base within a kstep

    // ---- resident B-fragments: W h-part, bf16 (shared by both batches) ----
    bf16x8 bF[4], bC[4];
#pragma unroll
    for (int ks = 0; ks < 4; ++ks) {
        const float* rF = Wf + (size_t)jj * ROWW + LSTM_E + 32*ks + kb;
        const float* rC = Wc + (size_t)jj * ROWW + LSTM_E + 32*ks + kb;
        float4 f0 = *(const float4*)rF, f1 = *(const float4*)(rF + 4);
        float4 c0 = *(const float4*)rC, c1 = *(const float4*)(rC + 4);
        float ef[8] = {f0.x,f0.y,f0.z,f0.w,f1.x,f1.y,f1.z,f1.w};
        float ec[8] = {c0.x,c0.y,c0.z,c0.w,c1.x,c1.y,c1.z,c1.w};
#pragma unroll
        for (int e = 0; e < 8; ++e) {
            bF[ks][e] = f2bf(ef[e]);
            bC[ks][e] = f2bf(ec[e]);
        }
        pin_frag(bF[ks]);   // <- r13: forbid re-sinking (r12: VGPR=52, chain
        pin_frag(bC[ks]);   //    reloaded per MFMA, 2x regression)
    }

    float cA = 0.0f, cB = 0.0f, hlA = 0.0f, hlB = 0.0f;
    if (t0 == 0) {
        if (tid < 2 * LSTM_H) {
            const int bb = tid >> 7, j = tid & 127;
            h_s[bb][0][j] = 0;
        }
    } else {
        if (tid < 2 * LSTM_H) {
            const int bb = tid >> 7, j = tid & 127;
            h_s[bb][0][j] = f2bf(state[(size_t)(b0 + bb) * LSTM_H + j]);
        }
        cA = state[LSTM_B * LSTM_H + (size_t)b0 * LSTM_H + jj];
        cB = state[LSTM_B * LSTM_H + (size_t)b1 * LSTM_H + jj];
    }

    const float* prepFA = pre + (size_t)b0 * LSTM_H + jj;      // [t][g=0][b][j]
    const float* prepCA = prepFA + LSTM_B * LSTM_H;            // g=1
    const float* prepFB = pre + (size_t)b1 * LSTM_H + jj;
    const float* prepCB = prepFB + LSTM_B * LSTM_H;
    const int NT = t1 - t0;
    float pfA0 = prepFA[0], pcA0 = prepCA[0];
    float pfB0 = prepFB[0], pcB0 = prepCB[0];
    float pfA1 = 0.f, pcA1 = 0.f, pfB1 = 0.f, pcB1 = 0.f;
    if (NT > 1) {
        pfA1 = prepFA[TSTRIDE]; pcA1 = prepCA[TSTRIDE];
        pfB1 = prepFB[TSTRIDE]; pcB1 = prepCB[TSTRIDE];
    }
    int offA = 2 * TSTRIDE;   // next A-load: step 2
    int offB = 2 * TSTRIDE;   // next B-load: step 2
    __syncthreads();          // h init visible (full drain once, harmless)

    const f32x4 zz = {0.f, 0.f, 0.f, 0.f};
    f32x4 mfAf = zz, mfAc = zz, mfBf = zz, mfBc = zz;

    // HALF1(RD, T): {read A-frags h_A[T], tail_B(T-1) -> write h_B[T],
    //                MFMA_A(T)} ; barrier.
#define HALF1(RD, T, DO_TAILB)                                                  \
    do {                                                                        \
        const short* hA_ = &h_s[0][RD][0];                                      \
        bf16x8 a0 = *(const bf16x8*)(hA_ + 0*32 + kb);                          \
        bf16x8 a1 = *(const bf16x8*)(hA_ + 1*32 + kb);                          \
        bf16x8 a2 = *(const bf16x8*)(hA_ + 2*32 + kb);                          \
        bf16x8 a3 = *(const bf16x8*)(hA_ + 3*32 + kb);                          \
        if (DO_TAILB) {                                                         \
            float afB = pfB0 + mfBf[0];                                         \
            float acB = pcB0 + mfBc[0];                                         \
            pfB0 = pfB1; pcB0 = pcB1;                                           \
            if ((T) + 1 < NT) { pfB1 = prepFB[offB]; pcB1 = prepCB[offB]; }     \
            offB += TSTRIDE;                                                    \
            float ggB = sigmoidf_(afB);                                         \
            float ctB = tanh_fast(acB);                                         \
            cB = ggB * (cB + ctB);                                              \
            float hnB = ggB * tanh_fast(cB);                                    \
            hlB = hnB;                                                          \
            if (lane < 16) h_s[1][RD][jj] = f2bf_hw(hnB);                       \
        }                                                                       \
        f32x4 tf = __builtin_amdgcn_mfma_f32_16x16x32_bf16(a0, bF[0], zz, 0,0,0);\
        f32x4 tc = __builtin_amdgcn_mfma_f32_16x16x32_bf16(a0, bC[0], zz, 0,0,0);\
        tf = __builtin_amdgcn_mfma_f32_16x16x32_bf16(a1, bF[1], tf, 0,0,0);     \
        tc = __builtin_amdgcn_mfma_f32_16x16x32_bf16(a1, bC[1], tc, 0,0,0);     \
        tf = __builtin_amdgcn_mfma_f32_16x16x32_bf16(a2, bF[2], tf, 0,0,0);     \
        tc = __builtin_amdgcn_mfma_f32_16x16x32_bf16(a2, bC[2], tc, 0,0,0);     \
        tf = __builtin_amdgcn_mfma_f32_16x16x32_bf16(a3, bF[3], tf, 0,0,0);     \
        tc = __builtin_amdgcn_mfma_f32_16x16x32_bf16(a3, bC[3], tc, 0,0,0);     \
        mfAf = tf; mfAc = tc;                                                   \
        lds_only_barrier();                                                     \
    } while (0)

    // HALF2(RD, WR, T): {read B-frags h_B[T], tail_A(T) -> write h_A[T+1],
    //                    MFMA_B(T)} ; barrier.
#define HALF2(RD, WR, T)                                                        \
    do {                                                                        \
        const short* hB_ = &h_s[1][RD][0];                                      \
        bf16x8 a0 = *(const bf16x8*)(hB_ + 0*32 + kb);                          \
        bf16x8 a1 = *(const bf16x8*)(hB_ + 1*32 + kb);                          \
        bf16x8 a2 = *(const bf16x8*)(hB_ + 2*32 + kb);                          \
        bf16x8 a3 = *(const bf16x8*)(hB_ + 3*32 + kb);                          \
        {                                                                       \
            float afA = pfA0 + mfAf[0];                                         \
            float acA = pcA0 + mfAc[0];                                         \
            pfA0 = pfA1; pcA0 = pcA1;                                           \
            if ((T) + 2 < NT) { pfA1 = prepFA[offA]; pcA1 = prepCA[offA]; }     \
            offA += TSTRIDE;                                                    \
            float ggA = sigmoidf_(afA);                                         \
            float ctA = tanh_fast(acA);                                         \
            cA = ggA * (cA + ctA);                                              \
            float hnA = ggA * tanh_fast(cA);                                    \
            hlA = hnA;                                                          \
            if (lane < 16) h_s[0][WR][jj] = f2bf_hw(hnA);                       \
        }                                                                       \
        f32x4 tf = __builtin_amdgcn_mfma_f32_16x16x32_bf16(a0, bF[0], zz, 0,0,0);\
        f32x4 tc = __builtin_amdgcn_mfma_f32_16x16x32_bf16(a0, bC[0], zz, 0,0,0);\
        tf = __builtin_amdgcn_mfma_f32_16x16x32_bf16(a1, bF[1], tf, 0,0,0);     \
        tc = __builtin_amdgcn_mfma_f32_16x16x32_bf16(a1, bC[1], tc, 0,0,0);     \
        tf = __builtin_amdgcn_mfma_f32_16x16x32_bf16(a2, bF[2], tf, 0,0,0);     \
        tc = __builtin_amdgcn_mfma_f32_16x16x32_bf16(a2, bC[2], tc, 0,0,0);     \
        tf = __builtin_amdgcn_mfma_f32_16x16x32_bf16(a3, bF[3], tf, 0,0,0);     \
        tc = __builtin_amdgcn_mfma_f32_16x16x32_bf16(a3, bC[3], tc, 0,0,0);     \
        mfBf = tf; mfBc = tc;                                                   \
        lds_only_barrier();                                                     \
    } while (0)

    // iteration 0 (buffers: read 0, write 1); no tail_B yet
    HALF1(0, 0, 0);
    HALF2(0, 1, 0);
    int t = 1;
    for (; t + 1 < NT; t += 2) {
        HALF1(1, t, 1);     HALF2(1, 0, t);
        HALF1(0, t + 1, 1); HALF2(0, 1, t + 1);
    }
    if (t < NT) { HALF1(1, t, 1); HALF2(1, 0, t); }
#undef HALF1
#undef HALF2

    // epilogue: tail_B(NT-1)
    {
        float afB = pfB0 + mfBf[0];
        float acB = pcB0 + mfBc[0];
        float ggB = sigmoidf_(afB);
        float ctB = tanh_fast(acB);
        cB = ggB * (cB + ctB);
        hlB = ggB * tanh_fast(cB);
    }

    if (t1 == S) {
        if (lane < 16) {
            red_s[0][jj] = hlA * Wfc[jj];
            red_s[1][jj] = hlB * Wfc[jj];
        }
        __syncthreads();
        if (tid < 128) {
            const int bb = tid >> 6;   // 0 or 1
            const int i  = tid & 63;
            float s = red_s[bb][i] + red_s[bb][i + 64];
            s += __shfl_down(s, 32, 64);
            s += __shfl_down(s, 16, 64);
            s += __shfl_down(s, 8, 64);
            s += __shfl_down(s, 4, 64);
            s += __shfl_down(s, 2, 64);
            s += __shfl_down(s, 1, 64);
            if (i == 0) out[b0 + bb] = sigmoidf_(s + bfc[0]);
        }
    } else {
        if (lane < 16) {
            state[(size_t)b0 * LSTM_H + jj] = hlA;
            state[(size_t)b1 * LSTM_H + jj] = hlB;
            state[LSTM_B * LSTM_H + (size_t)b0 * LSTM_H + jj] = cA;
            state[LSTM_B * LSTM_H + (size_t)b1 * LSTM_H + jj] = cB;
        }
    }
}

extern "C" void kernel_launch(void* const* d_in, const int* in_sizes, int n_in,
                              void* d_out, int out_size, void* d_ws, size_t ws_size,
                              hipStream_t stream) {
    const int*   x   = (const int*)d_in[0];
    const float* emb = (const float*)d_in[1];
    const float* Wf  = (const float*)d_in[2];
    const float* bf  = (const float*)d_in[3];
    const float* Wc  = (const float*)d_in[4];
    const float* bc  = (const float*)d_in[5];
    const float* Wfc = (const float*)d_in[6];
    const float* bfc = (const float*)d_in[7];
    float* out = (float*)d_out;

    const int S = in_sizes[0] / LSTM_B;           // 2048

    float* state = (float*)d_ws;                              // h[64][128], c[64][128]
    float* pre   = state + (size_t)2 * LSTM_B * LSTM_H;       // + 64KB

    const size_t state_bytes = (size_t)2 * LSTM_B * LSTM_H * sizeof(float);
    const size_t per_t_bytes = (size_t)TSTRIDE * sizeof(float);   // 64 KB per step
    size_t avail = (ws_size > state_bytes) ? (ws_size - state_bytes) : 0;
    int CH = (int)(avail / per_t_bytes);
    if (CH > S) CH = S;
    if (CH < 1) CH = 1;   // requires ws_size >= 128KB + state

    for (int t0 = 0; t0 < S; t0 += CH) {
        const int t1 = (t0 + CH < S) ? (t0 + CH) : S;
        const int nblocksA = ((t1 - t0) * LSTM_B + 127) / 128;
        lstm_phaseA<<<nblocksA, 512, 0, stream>>>(x, emb, Wf, bf, Wc, bc,
                                                  pre, t0, t1, S);
        lstm_phaseB<<<LSTM_B / 2, 512, 0, stream>>>(Wf, Wc, Wfc, bfc, pre, state,
                                                    out, t0, t1, S);
    }
}

// Round 14
// 695.542 us; speedup vs baseline: 2.1063x; 1.8182x over previous
//
#include <hip/hip_runtime.h>
#include <hip/hip_bf16.h>

// LSTM classifier: B=64, S=2048, E=H=128, OUT=1.  [REVERT to round-10 best: 694.8 us]
// Phase A (parallel, MFMA GEMM): pre[t][g][b][j] = bias + emb[x[b,t]].W_g[j][:128]
//   (~27 us steady-state, HBM-write bound: 167 MB traffic at ~6.2 TB/s.)
// Phase B (sequential, 1 WG/batch, 8 waves): h-matmul via mfma 16x16x32 bf16,
//   M=1, bf16 weights resident as B-fragments (VGPR=96).
// Structural floor (r8-r13 evidence): step ~775 cyc = 272 matrix (16 MFMA/SIMD
//   @ ~17 cyc, M=1 wastes 15/16 rows; no smaller bf16 shape exists) + serial
//   chain {ds_read 120 -> MFMA dep ~70 -> sigmoid/tanh/tanh tail ~130 ->
//   ds_write+barrier ~120} partially overlapped across 2 waves/SIMD.
//   Micro-edits (chain depth r9, barrier vmcnt semantics r10, prefetch depth
//   r4, VALU diet r7) all neutral; 2-batch overlap structures (r11/r12/r13)
//   all defeated by regalloc (weight remat/spill). Best = this kernel.

#define LSTM_B 64
#define LSTM_E 128
#define LSTM_H 128
#define ROWW   256           // E+H, weight row width
#define TSTRIDE (2*LSTM_B*LSTM_H)   // floats per timestep in pre buffer

typedef __attribute__((ext_vector_type(8))) short bf16x8;
typedef __attribute__((ext_vector_type(4))) float f32x4;

__device__ __forceinline__ float fast_rcp(float x) {
    return __builtin_amdgcn_rcpf(x);
}
__device__ __forceinline__ float sigmoidf_(float x) {
    return fast_rcp(1.0f + __expf(-x));
}
__device__ __forceinline__ float tanh_fast(float x) {
    float ax = fabsf(x);
    float t = __expf(-2.0f * ax);          // in (0,1], no overflow
    float r = (1.0f - t) * fast_rcp(1.0f + t);
    return copysignf(r, x);
}
__device__ __forceinline__ short f2bf(float f) {   // round-to-nearest-even
    union { float f; unsigned u; } v; v.f = f;
    unsigned r = (v.u + 0x7FFFu + ((v.u >> 16) & 1u)) >> 16;
    return (short)r;
}
__device__ __forceinline__ float bf2f(short s) {
    union { unsigned u; float f; } v; v.u = ((unsigned)(unsigned short)s) << 16;
    return v.f;
}
__device__ __forceinline__ short f2bf_hw(float f) {  // v_cvt_pk_bf16_f32 (RNE)
    unsigned r;
    float z = 0.0f;
    asm("v_cvt_pk_bf16_f32 %0, %1, %2" : "=v"(r) : "v"(f), "v"(z));
    return (short)(r & 0xFFFFu);
}

// Barrier that waits only on LDS ops (lgkmcnt(0)); vmcnt/expcnt untouched so
// global prefetch loads stay in flight across the barrier.
// waitcnt simm16: vmcnt[3:0]|[15:14]=63, expcnt[6:4]=7, lgkmcnt[11:8]=0 -> 0xC07F.
__device__ __forceinline__ void lds_only_barrier() {
    __builtin_amdgcn_s_waitcnt(0xC07F);
    __builtin_amdgcn_s_barrier();
}

// ---------------- Phase A: input projections, MFMA GEMM ----------------
// Block: 128 rows x 256 cols, 512 threads = 8 waves.
__global__ __launch_bounds__(512, 2) void lstm_phaseA(
    const int* __restrict__ x, const float* __restrict__ emb,
    const float* __restrict__ Wf, const float* __restrict__ bf,
    const float* __restrict__ Wc, const float* __restrict__ bc,
    float* __restrict__ pre, int t0, int t1, int S)
{
    __shared__ __align__(16) short a_hi[128][136];
    __shared__ __align__(16) short a_lo[128][136];
    __shared__ int idx_s[128];

    const int tid  = threadIdx.x;
    const int lane = tid & 63;
    const int w    = tid >> 6;
    const int r0   = blockIdx.x * 128;
    const int total_rows = (t1 - t0) * LSTM_B;
    const int nrows = (total_rows - r0 < 128) ? (total_rows - r0) : 128;

    if (tid < 128 && tid < nrows) {
        const int r = r0 + tid;
        idx_s[tid] = x[(size_t)(r & 63) * S + t0 + (r >> 6)];
    }
    __syncthreads();

    {   // gather emb rows -> bf16 hi/lo; 4 threads/row, staged, ds_write_b128
        const int row  = tid >> 2;
        const int part = (tid & 3) * 32;
        if (row < nrows) {
            const float* src = emb + (size_t)idx_s[row] * LSTM_E + part;
            bf16x8 vh[4], vl[4];
#pragma unroll
            for (int q = 0; q < 4; ++q) {
                float4 u = *(const float4*)(src + 8*q);
                float4 v = *(const float4*)(src + 8*q + 4);
                float e[8] = {u.x,u.y,u.z,u.w,v.x,v.y,v.z,v.w};
#pragma unroll
                for (int k = 0; k < 8; ++k) {
                    short h = f2bf(e[k]);
                    vh[q][k] = h;
                    vl[q][k] = f2bf(e[k] - bf2f(h));
                }
            }
#pragma unroll
            for (int q = 0; q < 4; ++q) {
                *(bf16x8*)&a_hi[row][part + 8*q] = vh[q];
                *(bf16x8*)&a_lo[row][part + 8*q] = vl[q];
            }
        }
    }

    // resident B-fragments: W E-part (cols 0..127), bf16
    const int jj = 16 * w + (lane & 15);
    const int kb = ((lane >> 4) & 3) * 8;
    bf16x8 bFr[4], bCr[4];
#pragma unroll
    for (int ks = 0; ks < 4; ++ks) {
        const float* rF = Wf + (size_t)jj * ROWW + 32*ks + kb;
        const float* rC = Wc + (size_t)jj * ROWW + 32*ks + kb;
        float4 f0 = *(const float4*)rF, f1 = *(const float4*)(rF + 4);
        float4 c0 = *(const float4*)rC, c1 = *(const float4*)(rC + 4);
        float ef[8] = {f0.x,f0.y,f0.z,f0.w,f1.x,f1.y,f1.z,f1.w};
        float ec[8] = {c0.x,c0.y,c0.z,c0.w,c1.x,c1.y,c1.z,c1.w};
#pragma unroll
        for (int e = 0; e < 8; ++e) { bFr[ks][e] = f2bf(ef[e]); bCr[ks][e] = f2bf(ec[e]); }
    }
    const float biasF = bf[jj], biasC = bc[jj];
    __syncthreads();

    f32x4 accF[8], accC[8];
#pragma unroll
    for (int m = 0; m < 8; ++m) {
        accF[m] = (f32x4){biasF, biasF, biasF, biasF};
        accC[m] = (f32x4){biasC, biasC, biasC, biasC};
    }

#pragma unroll
    for (int m = 0; m < 8; ++m) {
        const int ar = m * 16 + (lane & 15);
#pragma unroll
        for (int ks = 0; ks < 4; ++ks) {
            bf16x8 ah = *(const bf16x8*)&a_hi[ar][32*ks + kb];
            bf16x8 al = *(const bf16x8*)&a_lo[ar][32*ks + kb];
            accF[m] = __builtin_amdgcn_mfma_f32_16x16x32_bf16(ah, bFr[ks], accF[m], 0,0,0);
            accC[m] = __builtin_amdgcn_mfma_f32_16x16x32_bf16(ah, bCr[ks], accC[m], 0,0,0);
            accF[m] = __builtin_amdgcn_mfma_f32_16x16x32_bf16(al, bFr[ks], accF[m], 0,0,0);
            accC[m] = __builtin_amdgcn_mfma_f32_16x16x32_bf16(al, bCr[ks], accC[m], 0,0,0);
        }
    }

#pragma unroll
    for (int m = 0; m < 8; ++m) {
#pragma unroll
        for (int i = 0; i < 4; ++i) {
            const int rl = m * 16 + ((lane >> 4) & 3) * 4 + i;   // row in block
            if (rl < nrows) {
                const int r = r0 + rl;
                float* dst = pre + (size_t)(r >> 6) * TSTRIDE
                                 + (size_t)(r & 63) * LSTM_H + jj;
                dst[0]                 = accF[m][i];   // gate f plane
                dst[LSTM_B * LSTM_H]   = accC[m][i];   // gate c plane
            }
        }
    }
}

// ---------------- Phase B: the recurrence (MFMA) ----------------
// 64 blocks (1 batch each), 512 threads = 8 waves.
// Wave w, lane l: output j = 16*w + (l&15).
// B-frag: col n=l&15, k = 32*ks + 8*(l>>4) + e.  A-frag: broadcast row 0.
__global__ __launch_bounds__(512, 2) void lstm_phaseB(
    const float* __restrict__ Wf, const float* __restrict__ Wc,
    const float* __restrict__ Wfc, const float* __restrict__ bfc,
    const float* __restrict__ pre, float* __restrict__ state,
    float* __restrict__ out, int t0, int t1, int S)
{
    __shared__ __align__(16) short h_s[2][LSTM_H];   // bf16 h, double-buffered
    __shared__ float red_s[LSTM_H];

    const int b    = blockIdx.x;
    const int tid  = threadIdx.x;
    const int lane = tid & 63;
    const int w    = tid >> 6;          // wave 0..7
    const int jj   = 16 * w + (lane & 15);
    const int kb   = ((lane >> 4) & 3) * 8;   // k-sub-base within a kstep

    // ---- resident B-fragments: W h-part, bf16 ----
    bf16x8 bF[4], bC[4];
#pragma unroll
    for (int ks = 0; ks < 4; ++ks) {
        const float* rF = Wf + (size_t)jj * ROWW + LSTM_E + 32*ks + kb;
        const float* rC = Wc + (size_t)jj * ROWW + LSTM_E + 32*ks + kb;
        float4 f0 = *(const float4*)rF, f1 = *(const float4*)(rF + 4);
        float4 c0 = *(const float4*)rC, c1 = *(const float4*)(rC + 4);
        float ef[8] = {f0.x,f0.y,f0.z,f0.w,f1.x,f1.y,f1.z,f1.w};
        float ec[8] = {c0.x,c0.y,c0.z,c0.w,c1.x,c1.y,c1.z,c1.w};
#pragma unroll
        for (int e = 0; e < 8; ++e) {
            bF[ks][e] = f2bf(ef[e]);
            bC[ks][e] = f2bf(ec[e]);
        }
    }

    float c = 0.0f, h_last = 0.0f;
    if (t0 == 0) {
        if (tid < LSTM_H) h_s[0][tid] = 0;
    } else {
        if (tid < LSTM_H) h_s[0][tid] = f2bf(state[(size_t)b * LSTM_H + tid]);
        c = state[LSTM_B * LSTM_H + (size_t)b * LSTM_H + jj];
    }

    // pre stream, 2-deep prefetch; 2-body unroll, dedicated registers,
    // 32-bit element offsets.
    const float* prepF = pre + (size_t)b * LSTM_H + jj;        // [t][g=0][b][j]
    const float* prepC = prepF + LSTM_B * LSTM_H;              // g=1
    const int NT = t1 - t0;
    float pf0 = prepF[0], pc0 = prepC[0];
    float pf1 = 0.f, pc1 = 0.f;
    if (NT > 1) { pf1 = prepF[TSTRIDE]; pc1 = prepC[TSTRIDE]; }
    int off0 = 2 * TSTRIDE;   // body0 refill: even steps t+2
    int off1 = 3 * TSTRIDE;   // body1 refill: odd steps t+3
    __syncthreads();   // pre-loop: full drain once, harmless

    const f32x4 zz = {0.f, 0.f, 0.f, 0.f};

    // One timestep. MFMAs: 4 independent then 4 dependent (chain depth 2).
    // Step-end barrier = lgkmcnt(0)-only: prefetch VMEM stays in flight.
#define STEP_BODY(CUR, NXT, PF, PC, OFF, TLD)                                   \
    do {                                                                        \
        const short* hb = &h_s[CUR][0];                                         \
        bf16x8 a0 = *(const bf16x8*)(hb + 0*32 + kb);                           \
        bf16x8 a1 = *(const bf16x8*)(hb + 1*32 + kb);                           \
        bf16x8 a2 = *(const bf16x8*)(hb + 2*32 + kb);                           \
        bf16x8 a3 = *(const bf16x8*)(hb + 3*32 + kb);                           \
        float af_in = PF, ac_in = PC;                                           \
        if ((TLD) < NT) { PF = prepF[OFF]; PC = prepC[OFF]; }                   \
        OFF += 2 * TSTRIDE;                                                     \
        f32x4 fa = __builtin_amdgcn_mfma_f32_16x16x32_bf16(a0, bF[0], zz, 0,0,0);\
        f32x4 ga = __builtin_amdgcn_mfma_f32_16x16x32_bf16(a0, bC[0], zz, 0,0,0);\
        f32x4 fb = __builtin_amdgcn_mfma_f32_16x16x32_bf16(a2, bF[2], zz, 0,0,0);\
        f32x4 gb = __builtin_amdgcn_mfma_f32_16x16x32_bf16(a2, bC[2], zz, 0,0,0);\
        fa = __builtin_amdgcn_mfma_f32_16x16x32_bf16(a1, bF[1], fa, 0,0,0);     \
        ga = __builtin_amdgcn_mfma_f32_16x16x32_bf16(a1, bC[1], ga, 0,0,0);     \
        fb = __builtin_amdgcn_mfma_f32_16x16x32_bf16(a3, bF[3], fb, 0,0,0);     \
        gb = __builtin_amdgcn_mfma_f32_16x16x32_bf16(a3, bC[3], gb, 0,0,0);     \
        float af = af_in + (fa[0] + fb[0]);                                     \
        float ac = ac_in + (ga[0] + gb[0]);                                     \
        float gg = sigmoidf_(af);                                               \
        float ct = tanh_fast(ac);                                               \
        c = gg * (c + ct);                                                      \
        float hn = gg * tanh_fast(c);                                           \
        h_last = hn;                                                            \
        if (lane < 16) h_s[NXT][jj] = f2bf_hw(hn);                              \
        lds_only_barrier();                                                     \
    } while (0)

    int t = 0;
    for (; t + 1 < NT; t += 2) {
        STEP_BODY(0, 1, pf0, pc0, off0, t + 2);
        STEP_BODY(1, 0, pf1, pc1, off1, t + 3);
    }
    if (t < NT) { STEP_BODY(0, 1, pf0, pc0, off0, t + 2); }
#undef STEP_BODY

    if (t1 == S) {
        if (lane < 16) red_s[jj] = h_last * Wfc[jj];
        __syncthreads();
        if (tid < 64) {
            float s = red_s[tid] + red_s[tid + 64];
            s += __shfl_down(s, 32, 64);
            s += __shfl_down(s, 16, 64);
            s += __shfl_down(s, 8, 64);
            s += __shfl_down(s, 4, 64);
            s += __shfl_down(s, 2, 64);
            s += __shfl_down(s, 1, 64);
            if (tid == 0) out[b] = sigmoidf_(s + bfc[0]);
        }
    } else {
        if (lane < 16) {
            state[(size_t)b * LSTM_H + jj] = h_last;
            state[LSTM_B * LSTM_H + (size_t)b * LSTM_H + jj] = c;
        }
    }
}

extern "C" void kernel_launch(void* const* d_in, const int* in_sizes, int n_in,
                              void* d_out, int out_size, void* d_ws, size_t ws_size,
                              hipStream_t stream) {
    const int*   x   = (const int*)d_in[0];
    const float* emb = (const float*)d_in[1];
    const float* Wf  = (const float*)d_in[2];
    const float* bf  = (const float*)d_in[3];
    const float* Wc  = (const float*)d_in[4];
    const float* bc  = (const float*)d_in[5];
    const float* Wfc = (const float*)d_in[6];
    const float* bfc = (const float*)d_in[7];
    float* out = (float*)d_out;

    const int S = in_sizes[0] / LSTM_B;           // 2048

    float* state = (float*)d_ws;                              // h[64][128], c[64][128]
    float* pre   = state + (size_t)2 * LSTM_B * LSTM_H;       // + 64KB

    const size_t state_bytes = (size_t)2 * LSTM_B * LSTM_H * sizeof(float);
    const size_t per_t_bytes = (size_t)TSTRIDE * sizeof(float);   // 64 KB per step
    size_t avail = (ws_size > state_bytes) ? (ws_size - state_bytes) : 0;
    int CH = (int)(avail / per_t_bytes);
    if (CH > S) CH = S;
    if (CH < 1) CH = 1;   // requires ws_size >= 128KB + state

    for (int t0 = 0; t0 < S; t0 += CH) {
        const int t1 = (t0 + CH < S) ? (t0 + CH) : S;
        const int nblocksA = ((t1 - t0) * LSTM_B + 127) / 128;
        lstm_phaseA<<<nblocksA, 512, 0, stream>>>(x, emb, Wf, bf, Wc, bc,
                                                  pre, t0, t1, S);
        lstm_phaseB<<<LSTM_B, 512, 0, stream>>>(Wf, Wc, Wfc, bfc, pre, state,
                                                out, t0, t1, S);
    }
}